// Round 7
// baseline (103.635 us; speedup 1.0000x reference)
//
#include <hip/hip_runtime.h>
#include <stdint.h>

// Log-sparse causal attention, B=4 L=2048 H=8 E=D=64, fp32 in/out.
// Allowed distances delta = q - j: {0..7, 9, 13, 21, 37, 69, 133, 261, 517, 1029}
//
// R11: batched-gather design -- NO LDS, NO barrier, NO staging. Evidence from
// R4-R10: every stage->barrier->compute variant lands 33-43us with all pipes
// <15% busy; the macro-structure, not the schedule, is the suspect. Here each
// query owns 16 lanes (4 dims/lane), so one row-fragment = one float4 and ALL
// 17 K-row loads issue unconditionally back-to-back into 68 VGPRs (17-deep
// MLP per wave -- the thing R8's inline-V variant lacked at VGPR=44). Then:
// consume into 17 scores (shfl_xor 1,2,4,8 over the 16-lane group), issue the
// 17-row V batch into the just-freed K registers, softmax (hides V latency),
// PV FMAs, store. Two latency epochs/wave, fully overlapped across ~4
// waves/SIMD; no __syncthreads vmcnt drain anywhere.
// Dead deltas (q-del<0) clamp to row 0 -- one L2-hot 256B line per (b,h) --
// and are masked via sc=-inf -> p=0. No branches anywhere in the body.
// Guard metric vs R5 lesson: WRITE_SIZE must stay ~16.4MB (output only);
// spill would show as WRITE_SIZE inflation. VGPR target ~96-128, no
// launch_bounds min-occupancy arg.

static constexpr int Bn = 4, Ln = 2048, Hn = 8, En = 64;
static constexpr int QPB = 16;            // queries per block
static constexpr int NT  = 256;           // threads: 16 lanes/query x 16 queries
static constexpr int ND  = 17;

__global__ __launch_bounds__(NT) void logsparse_attn_kernel(
    const float* __restrict__ Q,
    const float* __restrict__ K,
    const float* __restrict__ V,
    float* __restrict__ O)
{
    constexpr int deltas[ND] = {0,1,2,3,4,5,6,7,9,13,21,37,69,133,261,517,1029};

    // 4096 blocks = 32 (b,h) x 128 query-chunks; bh = blockIdx%32 puts all
    // 128 chunks of one (b,h) on XCD (bh%8) under round-robin dispatch ->
    // that (b,h)'s 2MB K+V slice stays L2-local for the near-row reuse.
    const int bh = blockIdx.x & 31;
    const int l  = blockIdx.x >> 5;
    const int b  = bh >> 3;
    const int h  = bh & 7;
    const int q0 = l * QPB;

    const int tid = threadIdx.x;
    const size_t bhBase = ((size_t)b * Ln * Hn + (size_t)h) * (size_t)En;
    constexpr int ROWF = Hn * En;         // 512 floats between rows

    const int sub = tid & 15;             // 16 lanes/query, 4 dims each
    const int qq  = tid >> 4;             // query within block [0,16)
    const int q   = q0 + qq;
    const int dimOff = sub * 4;
    const size_t rowQ = bhBase + (size_t)q * ROWF + dimOff;

    // ---- Q fragment (4 floats), fold scale = 1/sqrt(64) ----
    const float4 qv = *(const float4*)(Q + rowQ);
    const float qf[4] = { qv.x*0.125f, qv.y*0.125f, qv.z*0.125f, qv.w*0.125f };

    // ---- epoch 1: batch-issue ALL 17 K-row loads (unconditional, clamped).
    // Full unroll + constant indices -> register-promoted, 17 loads in
    // flight before the first consume. ----
    float4 k[ND];
    #pragma unroll
    for (int d = 0; d < ND; ++d) {
        const int j  = q - deltas[d];
        const int jc = (j < 0) ? 0 : j;   // dead -> row 0 (L2-hot), masked below
        k[d] = *(const float4*)(K + bhBase + (size_t)jc * ROWF + dimOff);
    }

    // ---- consume K batch into 17 scores ----
    float sc[ND];
    #pragma unroll
    for (int d = 0; d < ND; ++d) {
        float s = qf[0]*k[d].x + qf[1]*k[d].y + qf[2]*k[d].z + qf[3]*k[d].w;
        s += __shfl_xor(s, 1);
        s += __shfl_xor(s, 2);
        s += __shfl_xor(s, 4);
        s += __shfl_xor(s, 8);
        sc[d] = (q - deltas[d] < 0) ? -__builtin_inff() : s;
    }

    // ---- epoch 2: batch-issue ALL 17 V-row loads into the freed K regs;
    // latency hides under the softmax VALU below. ----
    float4 v[ND];
    #pragma unroll
    for (int d = 0; d < ND; ++d) {
        const int j  = q - deltas[d];
        const int jc = (j < 0) ? 0 : j;
        v[d] = *(const float4*)(V + bhBase + (size_t)jc * ROWF + dimOff);
    }

    // ---- softmax over 17 scores (delta=0 always valid -> finite max) ----
    float m = sc[0];
    #pragma unroll
    for (int d = 1; d < ND; ++d) m = fmaxf(m, sc[d]);
    float sum = 0.0f;
    #pragma unroll
    for (int d = 0; d < ND; ++d) {
        sc[d] = __expf(sc[d] - m);        // exp(-inf)=0 for masked
        sum += sc[d];
    }
    const float inv = 1.0f / sum;

    // ---- PV: 17 unconditional weighted FMAs (w=0 for dead deltas) ----
    float acc[4] = {0,0,0,0};
    #pragma unroll
    for (int d = 0; d < ND; ++d) {
        const float w = sc[d];
        acc[0] = fmaf(w, v[d].x, acc[0]);
        acc[1] = fmaf(w, v[d].y, acc[1]);
        acc[2] = fmaf(w, v[d].z, acc[2]);
        acc[3] = fmaf(w, v[d].w, acc[3]);
    }

    float4 o;
    o.x = acc[0]*inv; o.y = acc[1]*inv; o.z = acc[2]*inv; o.w = acc[3]*inv;
    *(float4*)(O + rowQ) = o;             // 16 lanes x 16B = 256B contiguous
}

extern "C" void kernel_launch(void* const* d_in, const int* in_sizes, int n_in,
                              void* d_out, int out_size, void* d_ws, size_t ws_size,
                              hipStream_t stream) {
    const float* Q = (const float*)d_in[0];
    const float* K = (const float*)d_in[1];
    const float* V = (const float*)d_in[2];
    float* O = (float*)d_out;

    const int nblocks = Bn * Hn * (Ln / QPB);   // 4096 blocks, 16 queries each
    logsparse_attn_kernel<<<nblocks, NT, 0, stream>>>(Q, K, V, O);
}

// Round 9
// 101.606 us; speedup vs baseline: 1.0200x; 1.0200x over previous
//
#include <hip/hip_runtime.h>
#include <stdint.h>

// Log-sparse causal attention, B=4 L=2048 H=8 E=D=64, fp32 in/out.
// Allowed distances delta = q - j: {0..7, 9, 13, 21, 37, 69, 133, 261, 517, 1029}
//
// R12 = R6's kernel body (best measured: QPB=64/NT=512, K+V staged in LDS,
// NEAR_MAX=37, inline far loads, 2 blocks/CU = 16 waves/CU) with ONE change:
// the blockIdx -> (bh, l) mapping.  (Resubmission: previous round's bench
// died on container acquisition -- no measurement was taken.)
//
// Old mapping (R4-R11): bh = blockIdx&31 -> XCD x (= blockIdx&7 under
// round-robin dispatch) hosts slices bh in {x, x+8, x+16, x+24}: 16 MB of
// K+V on a 4 MB L2, and consecutive blocks on one XCD ROTATE through the 4
// slices -> every gather misses L2. With all pipes <15% busy across 8
// structural variants stuck at 33-43us, the limiter model is miss-path
// latency-capacity (~10 B/cyc/CU); the fix is L2 hit rate, not schedule.
//
// New mapping: x = i&7 (XCD), j = i>>3; bh = x*4 + (j>>5), l = j&31.
// Each XCD processes its 4 (b,h) slices SERIALLY; consecutive co-resident
// blocks walk l = 0..31 of the same slice. Active K+V slice = 4 MB = one
// XCD L2: staging spans of neighbors overlap (L2 hits), and far-delta rows
// (re-read at +69..+1029 by later chunks of the same slice on the same XCD)
// hit L2 instead of L3/HBM.
//
// 8 lanes/query x 8 dims; reduce = shfl_xor 1,2,4. PADF=68 (272 B rows)
// spreads ds_read_b128 bank starts -> max 2-way aliasing (free).
// Guard: WRITE_SIZE ~16.4 MB (no spill), VGPR/occupancy unchanged vs R6.

static constexpr int Bn = 4, Ln = 2048, Hn = 8, En = 64;
static constexpr int QPB = 64;            // queries per block
static constexpr int NT  = 512;           // threads per block (8 waves)
static constexpr int NEAR_MAX = 37;       // deltas <= this: staged in LDS
static constexpr int SPAN = NEAR_MAX + QPB;   // 101 rows: q0-37 .. q0+63
static constexpr int PADF = 68;           // floats per LDS row
static constexpr int NNEAR = 12;
static constexpr int NFAR  = 5;
static constexpr int NDELTA = NNEAR + NFAR;

__global__ __launch_bounds__(NT) void logsparse_attn_kernel(
    const float* __restrict__ Q,
    const float* __restrict__ K,
    const float* __restrict__ V,
    float* __restrict__ O)
{
    constexpr int nearD[NNEAR] = {0,1,2,3,4,5,6,7,9,13,21,37};
    constexpr int farD[NFAR]   = {69,133,261,517,1029};

    __shared__ float Ks[SPAN * PADF];
    __shared__ float Vs[SPAN * PADF];

    // ---- XCD-serial mapping (see header) ----
    const int i  = blockIdx.x;            // 1024 blocks
    const int x  = i & 7;                 // XCD under round-robin dispatch
    const int j  = i >> 3;                // 0..127, sequential on XCD x
    const int bh = x * 4 + (j >> 5);      // 4 slices per XCD, serial
    const int l  = j & 31;                // sequential 64-query chunks
    const int b  = bh >> 3;
    const int h  = bh & 7;
    const int q0 = l * QPB;

    const int tid = threadIdx.x;
    const size_t bhBase = ((size_t)b * Ln * Hn + (size_t)h) * (size_t)En;
    constexpr int ROWF = Hn * En;         // 512 floats between rows

    const int sub = tid & 7;              // 8 lanes/query, 8 dims each
    const int qq  = tid >> 3;             // query within block [0,64)
    const int q   = q0 + qq;
    const int dimOff = sub * 8;
    const size_t rowQ = bhBase + (size_t)q * ROWF + dimOff;

    // ---- Q load first (in flight across staging) ----
    const float4 q0v = *(const float4*)(Q + rowQ);
    const float4 q1v = *(const float4*)(Q + rowQ + 4);

    // ---- cooperative staging: 101 rows x 16 float4-chunks, K and V fused ----
    for (int idx = tid; idx < SPAN * 16; idx += NT) {
        const int rid = idx >> 4;
        const int ch  = idx & 15;
        int g = q0 - NEAR_MAX + rid;
        if (g < 0) g = 0;                 // finite data; masked later via p=0
        const size_t srcOff = bhBase + (size_t)g * ROWF + ch * 4;
        const int dst = rid * PADF + ch * 4;
        *(float4*)(Ks + dst) = *(const float4*)(K + srcOff);
        *(float4*)(Vs + dst) = *(const float4*)(V + srcOff);
    }

    // ---- Q chunk (8 floats), fold scale = 1/sqrt(64) ----
    const float qf[8] = { q0v.x*0.125f, q0v.y*0.125f, q0v.z*0.125f, q0v.w*0.125f,
                          q1v.x*0.125f, q1v.y*0.125f, q1v.z*0.125f, q1v.w*0.125f };

    __syncthreads();

    // ---- scores: 12 near (LDS) + 5 far (global, inline loads) ----
    float sc[NDELTA];
    #pragma unroll
    for (int d = 0; d < NNEAR; ++d) {
        const int del = nearD[d];
        const float* kp = Ks + (qq + NEAR_MAX - del) * PADF + dimOff;
        const float4 k0 = *(const float4*)(kp);
        const float4 k1 = *(const float4*)(kp + 4);
        float s = qf[0]*k0.x + qf[1]*k0.y + qf[2]*k0.z + qf[3]*k0.w
                + qf[4]*k1.x + qf[5]*k1.y + qf[6]*k1.z + qf[7]*k1.w;
        s += __shfl_xor(s, 1);
        s += __shfl_xor(s, 2);
        s += __shfl_xor(s, 4);
        sc[d] = (q - del < 0) ? -__builtin_inff() : s;
    }
    #pragma unroll
    for (int d = 0; d < NFAR; ++d) {
        const int del = farD[d];
        float s = -__builtin_inff();
        if (q0 + QPB - 1 >= del) {        // block-uniform: skip dead deltas
            const int jj = q - del;
            const int jc = (jj < 0) ? 0 : jj;  // p==0 later when jj<0
            const float* kp = K + bhBase + (size_t)jc * ROWF + dimOff;
            const float4 k0 = *(const float4*)(kp);
            const float4 k1 = *(const float4*)(kp + 4);
            float t = qf[0]*k0.x + qf[1]*k0.y + qf[2]*k0.z + qf[3]*k0.w
                    + qf[4]*k1.x + qf[5]*k1.y + qf[6]*k1.z + qf[7]*k1.w;
            t += __shfl_xor(t, 1);
            t += __shfl_xor(t, 2);
            t += __shfl_xor(t, 4);
            s = (jj < 0) ? -__builtin_inff() : t;
        }
        sc[NNEAR + d] = s;
    }

    // ---- softmax over 17 scores; p overwrites sc (register economy) ----
    float m = sc[0];
    #pragma unroll
    for (int d = 1; d < NDELTA; ++d) m = fmaxf(m, sc[d]);
    float sum = 0.0f;
    #pragma unroll
    for (int d = 0; d < NDELTA; ++d) {
        sc[d] = __expf(sc[d] - m);        // exp(-inf)=0 for masked
        sum += sc[d];
    }
    const float inv = 1.0f / sum;

    // ---- weighted sum of V rows: near from LDS, far from global inline ----
    float acc[8] = {0,0,0,0,0,0,0,0};
    #pragma unroll
    for (int d = 0; d < NNEAR; ++d) {
        const int del = nearD[d];
        const float* vp = Vs + (qq + NEAR_MAX - del) * PADF + dimOff;
        const float4 v0 = *(const float4*)(vp);
        const float4 v1 = *(const float4*)(vp + 4);
        const float w = sc[d];
        acc[0] = fmaf(w, v0.x, acc[0]);
        acc[1] = fmaf(w, v0.y, acc[1]);
        acc[2] = fmaf(w, v0.z, acc[2]);
        acc[3] = fmaf(w, v0.w, acc[3]);
        acc[4] = fmaf(w, v1.x, acc[4]);
        acc[5] = fmaf(w, v1.y, acc[5]);
        acc[6] = fmaf(w, v1.z, acc[6]);
        acc[7] = fmaf(w, v1.w, acc[7]);
    }
    #pragma unroll
    for (int d = 0; d < NFAR; ++d) {
        const int del = farD[d];
        if (q0 + QPB - 1 >= del) {        // uniform; p==0 covers jj<0 lanes
            const int jj = q - del;
            const int jc = (jj < 0) ? 0 : jj;
            const float* vp = V + bhBase + (size_t)jc * ROWF + dimOff;
            const float4 v0 = *(const float4*)(vp);
            const float4 v1 = *(const float4*)(vp + 4);
            const float w = sc[NNEAR + d];
            acc[0] = fmaf(w, v0.x, acc[0]);
            acc[1] = fmaf(w, v0.y, acc[1]);
            acc[2] = fmaf(w, v0.z, acc[2]);
            acc[3] = fmaf(w, v0.w, acc[3]);
            acc[4] = fmaf(w, v1.x, acc[4]);
            acc[5] = fmaf(w, v1.y, acc[5]);
            acc[6] = fmaf(w, v1.z, acc[6]);
            acc[7] = fmaf(w, v1.w, acc[7]);
        }
    }

    float4 o0, o1;
    o0.x = acc[0]*inv; o0.y = acc[1]*inv; o0.z = acc[2]*inv; o0.w = acc[3]*inv;
    o1.x = acc[4]*inv; o1.y = acc[5]*inv; o1.z = acc[6]*inv; o1.w = acc[7]*inv;
    *(float4*)(O + rowQ)     = o0;
    *(float4*)(O + rowQ + 4) = o1;
}

extern "C" void kernel_launch(void* const* d_in, const int* in_sizes, int n_in,
                              void* d_out, int out_size, void* d_ws, size_t ws_size,
                              hipStream_t stream) {
    const float* Q = (const float*)d_in[0];
    const float* K = (const float*)d_in[1];
    const float* V = (const float*)d_in[2];
    float* O = (float*)d_out;

    const int nblocks = Bn * Hn * (Ln / QPB);   // 1024 blocks, 64 queries each
    logsparse_attn_kernel<<<nblocks, NT, 0, stream>>>(Q, K, V, O);
}